// Round 8
// baseline (281.521 us; speedup 1.0000x reference)
//
#include <hip/hip_runtime.h>
#include <hip/hip_bf16.h>
#include <cstdint>
#include <cstddef>

#define DMODEL 1024
#define DINNER 2048
#define NSTATE 16
#define DTRANK 64
#define BATCH 2
#define SEQ 1024
#define ROWS (BATCH*SEQ)   // 2048 token rows
#define NCHUNK 16
#define CLEN (SEQ/NCHUNK)  // 64
#define KSPLIT 16          // split-K ways for x_proj GEMM

typedef __attribute__((ext_vector_type(8))) short short8;
typedef __attribute__((ext_vector_type(4))) float f32x4;

__device__ __forceinline__ float bf2f(__hip_bfloat16 h){ return __bfloat162float(h); }
__device__ __forceinline__ float sigmoidf_(float x){ return 1.0f/(1.0f + __expf(-x)); }

__device__ __forceinline__ void gld16(const void* g, void* l){
  __builtin_amdgcn_global_load_lds((const __attribute__((address_space(1))) void*)g,
                                   (__attribute__((address_space(3))) void*)l, 16, 0, 0);
}

// ---------------------------------------------------------------------------
// Fused canonicalizer + in-kernel dtype sniff + d_out zero-init.
// Sniff (validated R2..R7): per-wave count of bf16-exponent-in-range over the
// first 1024 halves of x; >=768 -> bf16 storage, else f32. Wave-uniform.
// ---------------------------------------------------------------------------
struct CvtArgs {
  const void *s0,*s1,*s2,*s3,*s4,*s5,*s6,*s7,*s8,*s9;
  __hip_bfloat16 *xB,*inpB,*xprojB,*dtprojB,*outpB;
  float *cwF,*cbF,*dtbF,*alF,*DF;
  float *outZ;                     // d_out zero-init (poisoned 0xAA each call)
};
#define CVT_C1 2097152
#define CVT_C2 6291456
#define CVT_C3 6299648
#define CVT_C4 6301696
#define CVT_C5 6498304
#define CVT_C6 6629376
#define CVT_C7 6631424
#define CVT_C8 6664192
#define CVT_C9 6666240
#define CVT_TOT 8763392

__device__ __forceinline__ float cvt_read(const void* s, int j, int fl){
  return fl ? ((const float*)s)[j] : bf2f(((const __hip_bfloat16*)s)[j]);
}

__global__ __launch_bounds__(256)
void convert_all_k(CvtArgs a)
{
  int i = blockIdx.x * 256 + threadIdx.x;
  // per-wave sniff over first 1024 halves of x (16 samples/lane)
  int lane = threadIdx.x & 63;
  const unsigned short* xu = (const unsigned short*)a.s0;
  int cnt = 0;
#pragma unroll
  for (int j = 0; j < 16; ++j) {
    unsigned short u = xu[lane*16 + j];
    int e = (u >> 7) & 0xFF;
    cnt += (e >= 0x70 && e <= 0x86) ? 1 : 0;
  }
#pragma unroll
  for (int o = 32; o; o >>= 1) cnt += __shfl_xor(cnt, o);
  const int fl = (cnt >= 768) ? 0 : 1;

  // zero d_out (2M floats) with the first 2048 blocks (f32x4 stores)
  if (blockIdx.x < 2048) {
    f32x4 z = {0.f, 0.f, 0.f, 0.f};
    ((f32x4*)a.outZ)[i] = z;
  }

  if (i >= CVT_TOT) return;
  if (i < CVT_C1)      a.xB[i]                = __float2bfloat16(cvt_read(a.s0, i, fl));
  else if (i < CVT_C2) a.inpB[i-CVT_C1]       = __float2bfloat16(cvt_read(a.s1, i-CVT_C1, fl));
  else if (i < CVT_C3) a.cwF[i-CVT_C2]        = cvt_read(a.s2, i-CVT_C2, fl);
  else if (i < CVT_C4) a.cbF[i-CVT_C3]        = cvt_read(a.s3, i-CVT_C3, fl);
  else if (i < CVT_C5) a.xprojB[i-CVT_C4]     = __float2bfloat16(cvt_read(a.s4, i-CVT_C4, fl));
  else if (i < CVT_C6) a.dtprojB[i-CVT_C5]    = __float2bfloat16(cvt_read(a.s5, i-CVT_C5, fl));
  else if (i < CVT_C7) a.dtbF[i-CVT_C6]       = cvt_read(a.s6, i-CVT_C6, fl);
  else if (i < CVT_C8) a.alF[i-CVT_C7]        = cvt_read(a.s7, i-CVT_C7, fl);
  else if (i < CVT_C9) a.DF[i-CVT_C8]         = cvt_read(a.s8, i-CVT_C8, fl);
  else                 a.outpB[i-CVT_C9]      = __float2bfloat16(cvt_read(a.s9, i-CVT_C9, fl));
}

// ---------------------------------------------------------------------------
// NT GEMM v2: BK=64 (32 MFMA per barrier — R7's BK=32 at K=1024 was
// barrier-drain bound at 320 TF), XOR-swizzled LDS staging.
// Swizzle: LDS slot (row, sg) holds global k-granule (sg ^ (row&7)); applied
// on the GLOBAL address so global_load_lds's lane-contiguous LDS constraint
// holds. Read side XORs back (involution). Spreads ds_read_b128 evenly over
// all 8 bank-groups (unswizzled BK=64 would hit only 4 -> 2x serialization).
// EPI: 3 = softplus(acc + biasF[col]) -> f32 (delta; K=64 -> single iter)
//      4 = in_proj split: col<2048 -> bf16 xi; col>=2048 -> silu -> f32 outF
//      5 = split-K partial: f32 -> outF + z*ROWS*96, cols<96 (x_proj)
//      6 = split-K atomic: unsafeAtomicAdd into outF [row,DMODEL] (out_proj)
// ---------------------------------------------------------------------------
template<int EPI>
__global__ __launch_bounds__(256)
void gemm64(const __hip_bfloat16* __restrict__ A,
            const __hip_bfloat16* __restrict__ W,
            int M, int N, int K, int kchunk,
            float* __restrict__ outF,
            __hip_bfloat16* __restrict__ outH,
            const float* __restrict__ biasF)
{
  __shared__ alignas(16) __hip_bfloat16 As[128*64];   // 16 KB
  __shared__ alignas(16) __hip_bfloat16 Ws[128*64];   // 16 KB
  const int tid  = threadIdx.x;
  const int lane = tid & 63;
  const int wave = tid >> 6;
  const int wm = wave & 1, wn = wave >> 1;
  const int row0 = blockIdx.y * 128;
  const int col0 = blockIdx.x * 128;

  f32x4 acc[4][4] = {};

  int kbeg = 0, kend = K;
  if (EPI == 5 || EPI == 6) { kbeg = blockIdx.z * kchunk; kend = kbeg + kchunk; }

  const int r16 = lane & 15, q = lane >> 4;
  const int sx0 = ((q ^ (r16 & 7)) * 16);     // ksub=0 swizzled byte offset
  // ksub=1 offset = sx0 ^ 64

  for (int k0 = kbeg; k0 < kend; k0 += 64) {
#pragma unroll
    for (int j = 0; j < 4; ++j) {             // A tile: 1024 granules of 16B
      int e = tid + j*256;
      int r = e >> 3, g = e & 7;
      int kc = ((g ^ (r & 7)) << 3);          // swizzled k-offset (elements)
      gld16(A + (size_t)(row0 + r) * K + k0 + kc, (char*)As + (size_t)e*16);
    }
#pragma unroll
    for (int j = 0; j < 4; ++j) {             // W tile
      int e = tid + j*256;
      int r = e >> 3, g = e & 7;
      int kc = ((g ^ (r & 7)) << 3);
      int rw = col0 + r; if (EPI == 5 && rw > N-1) rw = N-1;
      gld16(W + (size_t)rw * K + k0 + kc, (char*)Ws + (size_t)e*16);
    }
    __syncthreads();

    const char* Ab = (const char*)As + ((wm*64 + r16) * 128);
    const char* Wb = (const char*)Ws + ((wn*64 + r16) * 128);
#pragma unroll
    for (int ksub = 0; ksub < 2; ++ksub) {
      const int sx = sx0 ^ (ksub * 64);
      short8 af[4], wf[4];
#pragma unroll
      for (int i = 0; i < 4; ++i) af[i] = *(const short8*)(Ab + i*16*128 + sx);
#pragma unroll
      for (int i = 0; i < 4; ++i) wf[i] = *(const short8*)(Wb + i*16*128 + sx);
#pragma unroll
      for (int mt = 0; mt < 4; ++mt)
#pragma unroll
        for (int nt = 0; nt < 4; ++nt)
          acc[mt][nt] = __builtin_amdgcn_mfma_f32_16x16x32_bf16(af[mt], wf[nt], acc[mt][nt], 0, 0, 0);
    }
    __syncthreads();
  }

  // C/D layout (verified m89/m91): col = lane&15, row = (lane>>4)*4 + r
  const int mbase = row0 + wm*64 + (q * 4);
  const int nbase = col0 + wn*64 + r16;

  float bv[4];
  if (EPI == 3) {
#pragma unroll
    for (int nt = 0; nt < 4; ++nt) bv[nt] = biasF[nbase + nt*16];
  }

#pragma unroll
  for (int mt = 0; mt < 4; ++mt) {
#pragma unroll
    for (int nt = 0; nt < 4; ++nt) {
#pragma unroll
      for (int r = 0; r < 4; ++r) {
        int row = mbase + mt*16 + r;
        int col = nbase + nt*16;
        float v = acc[mt][nt][r];
        if (EPI == 3) {
          v += bv[nt];
          float sp = fmaxf(v, 0.0f) + __logf(1.0f + __expf(-fabsf(v)));
          outF[(size_t)row * DINNER + col] = sp;
        } else if (EPI == 4) {
          if (col < DINNER) {
            outH[(size_t)row * DINNER + col] = __float2bfloat16(v);
          } else {
            outF[(size_t)row * DINNER + (col - DINNER)] = v * sigmoidf_(v);
          }
        } else if (EPI == 5) {
          if (col < 96)
            outF[(size_t)blockIdx.z * (ROWS*96) + (size_t)row * 96 + col] = v;
        } else if (EPI == 6) {
          unsafeAtomicAdd(&outF[(size_t)row * DMODEL + col], v);
        }
      }
    }
  }
}

// ---------------------------------------------------------------------------
__global__ __launch_bounds__(256)
void reduce_xdbl_k(const float* __restrict__ part, float* __restrict__ xdbl,
                   __hip_bfloat16* __restrict__ dtH)
{
  int i = blockIdx.x * 256 + threadIdx.x;
  if (i >= ROWS*96) return;
  float s = 0.f;
#pragma unroll
  for (int kc = 0; kc < KSPLIT; ++kc) s += part[(size_t)kc*ROWS*96 + i];
  xdbl[i] = s;
  int row = i / 96, col = i - row*96;
  if (col < 64) dtH[(size_t)row*64 + col] = __float2bfloat16(s);
}

// ---------------------------------------------------------------------------
__global__ __launch_bounds__(256)
void conv_silu_k(const __hip_bfloat16* __restrict__ xi,
                 const float* __restrict__ cw,
                 const float* __restrict__ cb,
                 __hip_bfloat16* __restrict__ xcH)
{
  int idx = blockIdx.x * 256 + threadIdx.x;
  if (idx >= ROWS * DINNER) return;
  int d  = idx & (DINNER - 1);
  int t  = (idx >> 11) & (SEQ - 1);
  int bt = idx >> 11;
  float acc = cb[d];
#pragma unroll
  for (int i = 0; i < 4; ++i) {
    int tt = t - 3 + i;
    if (tt >= 0) acc += cw[d*4 + i] * bf2f(xi[(size_t)(bt - 3 + i) * DINNER + d]);
  }
  float y = acc * sigmoidf_(acc);
  xcH[idx] = __float2bfloat16(y);
}

// ---------------------------------------------------------------------------
// Chunked selective scan, v3 lane layout (validated R7): 4 lanes/channel,
// 4 states/lane, B/C staged once per block in LDS, 2 shfl_xor reduce.
// ---------------------------------------------------------------------------
#define GSTEP 8

__global__ __launch_bounds__(256)
void stats_k(const float* __restrict__ delta,
             const __hip_bfloat16* __restrict__ xcH,
             const float* __restrict__ xdbl,
             const float* __restrict__ alF,
             float* __restrict__ Hc, float* __restrict__ Sd)
{
  __shared__ alignas(16) float Bs[CLEN*16];     // 4 KB
  const int bid  = blockIdx.x;                  // b*512 + c*32 + cg
  const int b    = bid >> 9;
  const int c    = (bid >> 5) & (NCHUNK-1);
  const int cg   = bid & 31;
  const int tid  = threadIdx.x;
  const int lane = tid & 63;
  const int wave = tid >> 6;
  const int sub  = lane & 3;
  const int ch   = (cg << 6) + (wave << 4) + (lane >> 2);

  const size_t rb = (size_t)b * SEQ + (size_t)c * CLEN;

  for (int i = tid; i < CLEN*16; i += 256) {
    int t = i >> 4, j = i & 15;
    Bs[i] = xdbl[(rb + t)*96 + 64 + j];
  }
  __syncthreads();

  float negA[4];
#pragma unroll
  for (int j = 0; j < 4; ++j) negA[j] = -__expf(alF[ch*NSTATE + sub*4 + j]);

  const float*          dp = delta + rb * DINNER + ch;
  const __hip_bfloat16* xp = xcH   + rb * DINNER + ch;

  float h0=0.f,h1=0.f,h2=0.f,h3=0.f, sd=0.f;
  float d0[GSTEP], x0[GSTEP], d1[GSTEP], x1[GSTEP];

#define PF1(D_,X_,T0) \
  _Pragma("unroll") \
  for (int u = 0; u < GSTEP; ++u) { \
    D_[u] = dp[(size_t)((T0)+u) * DINNER]; \
    X_[u] = bf2f(xp[(size_t)((T0)+u) * DINNER]); \
  }
#define ST1(D_,X_,T0) \
  _Pragma("unroll") \
  for (int u = 0; u < GSTEP; ++u) { \
    float d_ = D_[u]; \
    sd += d_; \
    float du = d_ * X_[u]; \
    f32x4 B4 = *(const f32x4*)&Bs[((T0)+u)*16 + sub*4]; \
    h0 = __expf(d_*negA[0])*h0 + du*B4.x; \
    h1 = __expf(d_*negA[1])*h1 + du*B4.y; \
    h2 = __expf(d_*negA[2])*h2 + du*B4.z; \
    h3 = __expf(d_*negA[3])*h3 + du*B4.w; \
  }

  PF1(d0, x0, 0)
  for (int t0 = 0; t0 < CLEN; t0 += 2*GSTEP) {
    PF1(d1, x1, t0 + GSTEP)
    ST1(d0, x0, t0)
    if (t0 + 2*GSTEP < CLEN) { PF1(d0, x0, t0 + 2*GSTEP) }
    ST1(d1, x1, t0 + GSTEP)
  }
#undef PF1
#undef ST1

  const size_t bc = (size_t)(b*NCHUNK + c);
  f32x4 hv = { h0, h1, h2, h3 };
  *(f32x4*)&Hc[(bc*DINNER + ch)*NSTATE + sub*4] = hv;
  if (sub == 0) Sd[bc*DINNER + ch] = sd;
}

__global__ __launch_bounds__(256)
void carry_k(const float* __restrict__ Hc, const float* __restrict__ Sd,
             const float* __restrict__ alF, float* __restrict__ hin)
{
  int i = blockIdx.x * 256 + threadIdx.x;       // BATCH*DINNER*NSTATE = 65536
  int n  = i & (NSTATE-1);
  int ch = (i >> 4) & (DINNER-1);
  int b  = i >> 15;
  float negA = -__expf(alF[ch * NSTATE + n]);
  float h = 0.f;
#pragma unroll
  for (int c = 0; c < NCHUNK; ++c) {
    size_t bc = (size_t)(b*NCHUNK + c);
    hin[(bc*DINNER + ch)*NSTATE + n] = h;
    float P = __expf(negA * Sd[bc*DINNER + ch]);
    h = P * h + Hc[(bc*DINNER + ch)*NSTATE + n];
  }
}

__global__ __launch_bounds__(256)
void emit_k(const float* __restrict__ delta,
            const __hip_bfloat16* __restrict__ xcH,
            const float* __restrict__ xdbl,
            const float* __restrict__ zsF,
            const float* __restrict__ alF,
            const float* __restrict__ DF,
            const float* __restrict__ hin,
            __hip_bfloat16* __restrict__ yH)
{
  __shared__ alignas(16) float BCs[CLEN*32];    // 8 KB
  const int bid  = blockIdx.x;
  const int b    = bid >> 9;
  const int c    = (bid >> 5) & (NCHUNK-1);
  const int cg   = bid & 31;
  const int tid  = threadIdx.x;
  const int lane = tid & 63;
  const int wave = tid >> 6;
  const int sub  = lane & 3;
  const int ch   = (cg << 6) + (wave << 4) + (lane >> 2);

  const size_t rb = (size_t)b * SEQ + (size_t)c * CLEN;

  for (int i = tid; i < CLEN*32; i += 256) {
    int t = i >> 5, j = i & 31;
    BCs[i] = xdbl[(rb + t)*96 + 64 + j];
  }
  __syncthreads();

  float negA[4];
#pragma unroll
  for (int j = 0; j < 4; ++j) negA[j] = -__expf(alF[ch*NSTATE + sub*4 + j]);
  const float Dch = DF[ch];

  const float*          dp = delta + rb * DINNER + ch;
  const __hip_bfloat16* xp = xcH   + rb * DINNER + ch;
  const float*          zp = zsF   + rb * DINNER + ch;
  __hip_bfloat16*       yp = yH    + rb * DINNER + ch;

  f32x4 hv = *(const f32x4*)&hin[((size_t)(b*NCHUNK + c)*DINNER + ch)*NSTATE + sub*4];
  float h0=hv.x, h1=hv.y, h2=hv.z, h3=hv.w;

  float d0[GSTEP], x0[GSTEP], z0[GSTEP], d1[GSTEP], x1[GSTEP], z1[GSTEP];

#define PF(D_,X_,Z_,T0) \
  _Pragma("unroll") \
  for (int u = 0; u < GSTEP; ++u) { \
    D_[u] = dp[(size_t)((T0)+u) * DINNER]; \
    X_[u] = bf2f(xp[(size_t)((T0)+u) * DINNER]); \
    Z_[u] = zp[(size_t)((T0)+u) * DINNER]; \
  }
#define STEPS(D_,X_,Z_,T0) \
  _Pragma("unroll") \
  for (int u = 0; u < GSTEP; ++u) { \
    float d_ = D_[u]; \
    float du = d_ * X_[u]; \
    f32x4 B4 = *(const f32x4*)&BCs[((T0)+u)*32 + sub*4]; \
    f32x4 C4 = *(const f32x4*)&BCs[((T0)+u)*32 + 16 + sub*4]; \
    h0 = __expf(d_*negA[0])*h0 + du*B4.x; \
    h1 = __expf(d_*negA[1])*h1 + du*B4.y; \
    h2 = __expf(d_*negA[2])*h2 + du*B4.z; \
    h3 = __expf(d_*negA[3])*h3 + du*B4.w; \
    float p = h0*C4.x + h1*C4.y + h2*C4.z + h3*C4.w; \
    p += __shfl_xor(p, 1); \
    p += __shfl_xor(p, 2); \
    if (sub == 0) { \
      float y = (p + X_[u] * Dch) * Z_[u]; \
      yp[(size_t)((T0)+u) * DINNER] = __float2bfloat16(y); \
    } \
  }

  PF(d0, x0, z0, 0)
  for (int t0 = 0; t0 < CLEN; t0 += 2*GSTEP) {
    PF(d1, x1, z1, t0 + GSTEP)
    STEPS(d0, x0, z0, t0)
    if (t0 + 2*GSTEP < CLEN) { PF(d0, x0, z0, t0 + 2*GSTEP) }
    STEPS(d1, x1, z1, t0 + GSTEP)
  }
#undef PF
#undef STEPS
}

// ---------------------------------------------------------------------------
extern "C" void kernel_launch(void* const* d_in, const int* in_sizes, int n_in,
                              void* d_out, int out_size, void* d_ws, size_t ws_size,
                              hipStream_t stream)
{
  float* out = (float*)d_out;   // reference output dtype: float32
  char* ws = (char*)d_ws;
  const size_t MB = 1024*1024;

  // workspace layout (68 MB, liveness-aliased)
  float*          cwF     = (float*)          (ws + 1024);
  float*          cbF     = (float*)          (ws + 40*1024);
  float*          dtbF    = (float*)          (ws + 56*1024);
  float*          alF     = (float*)          (ws + 72*1024);
  float*          DF      = (float*)          (ws + 208*1024);
  float*          Sd      = (float*)          (ws + 256*1024);      // 256 KB
  __hip_bfloat16* xB      = (__hip_bfloat16*) (ws + 1*MB);          // 4 MB  (dead after G1)
  __hip_bfloat16* inpB    = (__hip_bfloat16*) (ws + 5*MB);          // 8 MB  (dead after G1)
  __hip_bfloat16* xiB     = (__hip_bfloat16*) (ws + 13*MB);         // 8 MB  (dead after conv)
  float*          part    = (float*)          (ws + 1*MB);          // 12 MB aliases xB/inpB
  float*          dlt     = (float*)          (ws + 1*MB);          // 16 MB aliases part/xiB[:4MB]
  __hip_bfloat16* xprojB  = (__hip_bfloat16*) (ws + 21*MB);
  __hip_bfloat16* dtprojB = (__hip_bfloat16*) (ws + 21*MB + 512*1024);
  __hip_bfloat16* outpB   = (__hip_bfloat16*) (ws + 22*MB);         // 4 MB
  float*          zsF     = (float*)          (ws + 26*MB);         // 16 MB
  __hip_bfloat16* xcH     = (__hip_bfloat16*) (ws + 42*MB);         // 8 MB
  float*          xdbl    = (float*)          (ws + 50*MB);         // 768 KB
  __hip_bfloat16* dtH     = (__hip_bfloat16*) (ws + 51*MB);         // 256 KB
  __hip_bfloat16* yH      = (__hip_bfloat16*) (ws + 52*MB);         // 8 MB
  float*          Hc      = (float*)          (ws + 60*MB);         // 4 MB
  float*          hin     = (float*)          (ws + 64*MB);         // 4 MB -> top 68 MB

  dim3 blk(256);

  // 0) canonicalize (+ in-kernel sniff + d_out zero-init)
  CvtArgs ca = { d_in[0], d_in[1], d_in[2], d_in[3], d_in[4],
                 d_in[5], d_in[6], d_in[7], d_in[8], d_in[9],
                 xB, inpB, xprojB, dtprojB, outpB,
                 cwF, cbF, dtbF, alF, DF, out };
  convert_all_k<<<CVT_TOT/256, blk, 0, stream>>>(ca);

  // 1) in_proj (2048 x 4096 x 1024): split -> xi bf16, silu(z) f32
  gemm64<4><<<dim3(4096/128, ROWS/128), blk, 0, stream>>>(
      xB, inpB, ROWS, 2*DINNER, DMODEL, 0, zsF, xiB, nullptr);

  // 2) xc = silu(depthwise_conv(xi) + b)
  conv_silu_k<<<(ROWS*DINNER)/256, blk, 0, stream>>>(xiB, cwF, cbF, xcH);

  // 3) x_dbl (2048 x 96 x 2048): 16-way split-K (kchunk=128 -> 2 iters) + reduce
  gemm64<5><<<dim3(1, ROWS/128, KSPLIT), blk, 0, stream>>>(
      xcH, xprojB, ROWS, 96, DINNER, DINNER/KSPLIT, part, nullptr, nullptr);
  reduce_xdbl_k<<<(ROWS*96+255)/256, blk, 0, stream>>>(part, xdbl, dtH);

  // 4) delta = softplus(dt @ dt_proj^T + dt_b) (2048 x 2048 x 64): single K-iter
  gemm64<3><<<dim3(DINNER/128, ROWS/128), blk, 0, stream>>>(
      dtH, dtprojB, ROWS, DINNER, DTRANK, 0, dlt, nullptr, dtbF);

  // 5) chunked selective scan + fused combine -> bf16 yH
  stats_k<<<BATCH*NCHUNK*32, blk, 0, stream>>>(dlt, xcH, xdbl, alF, Hc, Sd);
  carry_k<<<(BATCH*DINNER*NSTATE)/256, blk, 0, stream>>>(Hc, Sd, alF, hin);
  emit_k<<<BATCH*NCHUNK*32, blk, 0, stream>>>(dlt, xcH, xdbl, zsF, alF, DF, hin, yH);

  // 6) out_proj (2048 x 1024 x 2048): split-K=4, atomic accumulate into d_out
  gemm64<6><<<dim3(DMODEL/128, ROWS/128, 4), blk, 0, stream>>>(
      yH, outpB, ROWS, DMODEL, DINNER, DINNER/4, out, nullptr, nullptr);
}

// Round 9
// 264.219 us; speedup vs baseline: 1.0655x; 1.0655x over previous
//
#include <hip/hip_runtime.h>
#include <hip/hip_bf16.h>
#include <cstdint>
#include <cstddef>

#define DMODEL 1024
#define DINNER 2048
#define NSTATE 16
#define DTRANK 64
#define BATCH 2
#define SEQ 1024
#define ROWS (BATCH*SEQ)   // 2048 token rows
#define NCHUNK 16
#define CLEN (SEQ/NCHUNK)  // 64
#define KSPLIT 16          // split-K ways for x_proj GEMM

typedef __attribute__((ext_vector_type(8))) short short8;
typedef __attribute__((ext_vector_type(4))) float f32x4;

__device__ __forceinline__ float bf2f(__hip_bfloat16 h){ return __bfloat162float(h); }
__device__ __forceinline__ float sigmoidf_(float x){ return 1.0f/(1.0f + __expf(-x)); }

__device__ __forceinline__ void gld16(const void* g, void* l){
  __builtin_amdgcn_global_load_lds((const __attribute__((address_space(1))) void*)g,
                                   (__attribute__((address_space(3))) void*)l, 16, 0, 0);
}

// ---------------------------------------------------------------------------
// dtype sniffer — SEPARATE tiny kernel (R8 inlined this per-thread in the
// convert kernel: 8.7M threads x 16 scalar loads = 140M VMEM insts = +30us.
// One 64-thread block amortizes it to ~0).
// ---------------------------------------------------------------------------
__global__ void sniff_k(const unsigned short* __restrict__ xu, int* __restrict__ flag)
{
  int t = threadIdx.x;           // 64 threads
  int cnt = 0;
  for (int i = t; i < 1024; i += 64) {
    unsigned short u = xu[i];
    int e = (u >> 7) & 0xFF;
    if (e >= 0x70 && e <= 0x86) cnt++;
  }
  for (int o = 32; o; o >>= 1) cnt += __shfl_down(cnt, o);
  if (t == 0) *flag = (cnt >= 768) ? 0 : 1;
}

// ---------------------------------------------------------------------------
// Fused canonicalizer (reads broadcast *flag) + d_out zero-init.
// ---------------------------------------------------------------------------
struct CvtArgs {
  const void *s0,*s1,*s2,*s3,*s4,*s5,*s6,*s7,*s8,*s9;
  __hip_bfloat16 *xB,*inpB,*xprojB,*dtprojB,*outpB;
  float *cwF,*cbF,*dtbF,*alF,*DF;
  float *outZ;                     // d_out zero-init (poisoned 0xAA each call)
  const int* flag;
};
#define CVT_C1 2097152
#define CVT_C2 6291456
#define CVT_C3 6299648
#define CVT_C4 6301696
#define CVT_C5 6498304
#define CVT_C6 6629376
#define CVT_C7 6631424
#define CVT_C8 6664192
#define CVT_C9 6666240
#define CVT_TOT 8763392

__device__ __forceinline__ float cvt_read(const void* s, int j, int fl){
  return fl ? ((const float*)s)[j] : bf2f(((const __hip_bfloat16*)s)[j]);
}

__global__ __launch_bounds__(256)
void convert_all_k(CvtArgs a)
{
  int i = blockIdx.x * 256 + threadIdx.x;
  const int fl = *a.flag;

  // zero d_out (2M floats) with the first 2048 blocks (f32x4 stores)
  if (blockIdx.x < 2048) {
    f32x4 z = {0.f, 0.f, 0.f, 0.f};
    ((f32x4*)a.outZ)[i] = z;
  }

  if (i >= CVT_TOT) return;
  if (i < CVT_C1)      a.xB[i]                = __float2bfloat16(cvt_read(a.s0, i, fl));
  else if (i < CVT_C2) a.inpB[i-CVT_C1]       = __float2bfloat16(cvt_read(a.s1, i-CVT_C1, fl));
  else if (i < CVT_C3) a.cwF[i-CVT_C2]        = cvt_read(a.s2, i-CVT_C2, fl);
  else if (i < CVT_C4) a.cbF[i-CVT_C3]        = cvt_read(a.s3, i-CVT_C3, fl);
  else if (i < CVT_C5) a.xprojB[i-CVT_C4]     = __float2bfloat16(cvt_read(a.s4, i-CVT_C4, fl));
  else if (i < CVT_C6) a.dtprojB[i-CVT_C5]    = __float2bfloat16(cvt_read(a.s5, i-CVT_C5, fl));
  else if (i < CVT_C7) a.dtbF[i-CVT_C6]       = cvt_read(a.s6, i-CVT_C6, fl);
  else if (i < CVT_C8) a.alF[i-CVT_C7]        = cvt_read(a.s7, i-CVT_C7, fl);
  else if (i < CVT_C9) a.DF[i-CVT_C8]         = cvt_read(a.s8, i-CVT_C8, fl);
  else                 a.outpB[i-CVT_C9]      = __float2bfloat16(cvt_read(a.s9, i-CVT_C9, fl));
}

// ---------------------------------------------------------------------------
// NT GEMM v2 (validated R8: in_proj 53.8 -> <43.5us): BK=64 (32 MFMA per
// barrier), XOR-swizzled LDS staging (swizzle applied on the GLOBAL address
// so global_load_lds's lane-contiguous LDS constraint holds; read side XORs
// back — involution).
// EPI: 3 = softplus(acc + biasF[col]) -> f32 (delta; K=64 -> single iter)
//      4 = in_proj split: col<2048 -> bf16 xi; col>=2048 -> silu -> f32 outF
//      5 = split-K partial: f32 -> outF + z*ROWS*96, cols<96 (x_proj)
//      6 = split-K atomic: unsafeAtomicAdd into outF [row,DMODEL] (out_proj)
// ---------------------------------------------------------------------------
template<int EPI>
__global__ __launch_bounds__(256)
void gemm64(const __hip_bfloat16* __restrict__ A,
            const __hip_bfloat16* __restrict__ W,
            int M, int N, int K, int kchunk,
            float* __restrict__ outF,
            __hip_bfloat16* __restrict__ outH,
            const float* __restrict__ biasF)
{
  __shared__ alignas(16) __hip_bfloat16 As[128*64];   // 16 KB
  __shared__ alignas(16) __hip_bfloat16 Ws[128*64];   // 16 KB
  const int tid  = threadIdx.x;
  const int lane = tid & 63;
  const int wave = tid >> 6;
  const int wm = wave & 1, wn = wave >> 1;
  const int row0 = blockIdx.y * 128;
  const int col0 = blockIdx.x * 128;

  f32x4 acc[4][4] = {};

  int kbeg = 0, kend = K;
  if (EPI == 5 || EPI == 6) { kbeg = blockIdx.z * kchunk; kend = kbeg + kchunk; }

  const int r16 = lane & 15, q = lane >> 4;
  const int sx0 = ((q ^ (r16 & 7)) * 16);     // ksub=0 swizzled byte offset

  for (int k0 = kbeg; k0 < kend; k0 += 64) {
#pragma unroll
    for (int j = 0; j < 4; ++j) {             // A tile: 1024 granules of 16B
      int e = tid + j*256;
      int r = e >> 3, g = e & 7;
      int kc = ((g ^ (r & 7)) << 3);          // swizzled k-offset (elements)
      gld16(A + (size_t)(row0 + r) * K + k0 + kc, (char*)As + (size_t)e*16);
    }
#pragma unroll
    for (int j = 0; j < 4; ++j) {             // W tile
      int e = tid + j*256;
      int r = e >> 3, g = e & 7;
      int kc = ((g ^ (r & 7)) << 3);
      int rw = col0 + r; if (EPI == 5 && rw > N-1) rw = N-1;
      gld16(W + (size_t)rw * K + k0 + kc, (char*)Ws + (size_t)e*16);
    }
    __syncthreads();

    const char* Ab = (const char*)As + ((wm*64 + r16) * 128);
    const char* Wb = (const char*)Ws + ((wn*64 + r16) * 128);
#pragma unroll
    for (int ksub = 0; ksub < 2; ++ksub) {
      const int sx = sx0 ^ (ksub * 64);
      short8 af[4], wf[4];
#pragma unroll
      for (int i = 0; i < 4; ++i) af[i] = *(const short8*)(Ab + i*16*128 + sx);
#pragma unroll
      for (int i = 0; i < 4; ++i) wf[i] = *(const short8*)(Wb + i*16*128 + sx);
#pragma unroll
      for (int mt = 0; mt < 4; ++mt)
#pragma unroll
        for (int nt = 0; nt < 4; ++nt)
          acc[mt][nt] = __builtin_amdgcn_mfma_f32_16x16x32_bf16(af[mt], wf[nt], acc[mt][nt], 0, 0, 0);
    }
    __syncthreads();
  }

  // C/D layout (verified m89/m91): col = lane&15, row = (lane>>4)*4 + r
  const int mbase = row0 + wm*64 + (q * 4);
  const int nbase = col0 + wn*64 + r16;

  float bv[4];
  if (EPI == 3) {
#pragma unroll
    for (int nt = 0; nt < 4; ++nt) bv[nt] = biasF[nbase + nt*16];
  }

#pragma unroll
  for (int mt = 0; mt < 4; ++mt) {
#pragma unroll
    for (int nt = 0; nt < 4; ++nt) {
#pragma unroll
      for (int r = 0; r < 4; ++r) {
        int row = mbase + mt*16 + r;
        int col = nbase + nt*16;
        float v = acc[mt][nt][r];
        if (EPI == 3) {
          v += bv[nt];
          float sp = fmaxf(v, 0.0f) + __logf(1.0f + __expf(-fabsf(v)));
          outF[(size_t)row * DINNER + col] = sp;
        } else if (EPI == 4) {
          if (col < DINNER) {
            outH[(size_t)row * DINNER + col] = __float2bfloat16(v);
          } else {
            outF[(size_t)row * DINNER + (col - DINNER)] = v * sigmoidf_(v);
          }
        } else if (EPI == 5) {
          if (col < 96)
            outF[(size_t)blockIdx.z * (ROWS*96) + (size_t)row * 96 + col] = v;
        } else if (EPI == 6) {
          unsafeAtomicAdd(&outF[(size_t)row * DMODEL + col], v);
        }
      }
    }
  }
}

// ---------------------------------------------------------------------------
__global__ __launch_bounds__(256)
void reduce_xdbl_k(const float* __restrict__ part, float* __restrict__ xdbl,
                   __hip_bfloat16* __restrict__ dtH)
{
  int i = blockIdx.x * 256 + threadIdx.x;
  if (i >= ROWS*96) return;
  float s = 0.f;
#pragma unroll
  for (int kc = 0; kc < KSPLIT; ++kc) s += part[(size_t)kc*ROWS*96 + i];
  xdbl[i] = s;
  int row = i / 96, col = i - row*96;
  if (col < 64) dtH[(size_t)row*64 + col] = __float2bfloat16(s);
}

// ---------------------------------------------------------------------------
__global__ __launch_bounds__(256)
void conv_silu_k(const __hip_bfloat16* __restrict__ xi,
                 const float* __restrict__ cw,
                 const float* __restrict__ cb,
                 __hip_bfloat16* __restrict__ xcH)
{
  int idx = blockIdx.x * 256 + threadIdx.x;
  if (idx >= ROWS * DINNER) return;
  int d  = idx & (DINNER - 1);
  int t  = (idx >> 11) & (SEQ - 1);
  int bt = idx >> 11;
  float acc = cb[d];
#pragma unroll
  for (int i = 0; i < 4; ++i) {
    int tt = t - 3 + i;
    if (tt >= 0) acc += cw[d*4 + i] * bf2f(xi[(size_t)(bt - 3 + i) * DINNER + d]);
  }
  float y = acc * sigmoidf_(acc);
  xcH[idx] = __float2bfloat16(y);
}

// ---------------------------------------------------------------------------
// Chunked selective scan, v3 lane layout (validated R7): 4 lanes/channel,
// 4 states/lane, B/C staged once per block in LDS, 2 shfl_xor reduce.
// ---------------------------------------------------------------------------
#define GSTEP 8

__global__ __launch_bounds__(256)
void stats_k(const float* __restrict__ delta,
             const __hip_bfloat16* __restrict__ xcH,
             const float* __restrict__ xdbl,
             const float* __restrict__ alF,
             float* __restrict__ Hc, float* __restrict__ Sd)
{
  __shared__ alignas(16) float Bs[CLEN*16];     // 4 KB
  const int bid  = blockIdx.x;                  // b*512 + c*32 + cg
  const int b    = bid >> 9;
  const int c    = (bid >> 5) & (NCHUNK-1);
  const int cg   = bid & 31;
  const int tid  = threadIdx.x;
  const int lane = tid & 63;
  const int wave = tid >> 6;
  const int sub  = lane & 3;
  const int ch   = (cg << 6) + (wave << 4) + (lane >> 2);

  const size_t rb = (size_t)b * SEQ + (size_t)c * CLEN;

  for (int i = tid; i < CLEN*16; i += 256) {
    int t = i >> 4, j = i & 15;
    Bs[i] = xdbl[(rb + t)*96 + 64 + j];
  }
  __syncthreads();

  float negA[4];
#pragma unroll
  for (int j = 0; j < 4; ++j) negA[j] = -__expf(alF[ch*NSTATE + sub*4 + j]);

  const float*          dp = delta + rb * DINNER + ch;
  const __hip_bfloat16* xp = xcH   + rb * DINNER + ch;

  float h0=0.f,h1=0.f,h2=0.f,h3=0.f, sd=0.f;
  float d0[GSTEP], x0[GSTEP], d1[GSTEP], x1[GSTEP];

#define PF1(D_,X_,T0) \
  _Pragma("unroll") \
  for (int u = 0; u < GSTEP; ++u) { \
    D_[u] = dp[(size_t)((T0)+u) * DINNER]; \
    X_[u] = bf2f(xp[(size_t)((T0)+u) * DINNER]); \
  }
#define ST1(D_,X_,T0) \
  _Pragma("unroll") \
  for (int u = 0; u < GSTEP; ++u) { \
    float d_ = D_[u]; \
    sd += d_; \
    float du = d_ * X_[u]; \
    f32x4 B4 = *(const f32x4*)&Bs[((T0)+u)*16 + sub*4]; \
    h0 = __expf(d_*negA[0])*h0 + du*B4.x; \
    h1 = __expf(d_*negA[1])*h1 + du*B4.y; \
    h2 = __expf(d_*negA[2])*h2 + du*B4.z; \
    h3 = __expf(d_*negA[3])*h3 + du*B4.w; \
  }

  PF1(d0, x0, 0)
  for (int t0 = 0; t0 < CLEN; t0 += 2*GSTEP) {
    PF1(d1, x1, t0 + GSTEP)
    ST1(d0, x0, t0)
    if (t0 + 2*GSTEP < CLEN) { PF1(d0, x0, t0 + 2*GSTEP) }
    ST1(d1, x1, t0 + GSTEP)
  }
#undef PF1
#undef ST1

  const size_t bc = (size_t)(b*NCHUNK + c);
  f32x4 hv = { h0, h1, h2, h3 };
  *(f32x4*)&Hc[(bc*DINNER + ch)*NSTATE + sub*4] = hv;
  if (sub == 0) Sd[bc*DINNER + ch] = sd;
}

__global__ __launch_bounds__(256)
void carry_k(const float* __restrict__ Hc, const float* __restrict__ Sd,
             const float* __restrict__ alF, float* __restrict__ hin)
{
  int i = blockIdx.x * 256 + threadIdx.x;       // BATCH*DINNER*NSTATE = 65536
  int n  = i & (NSTATE-1);
  int ch = (i >> 4) & (DINNER-1);
  int b  = i >> 15;
  float negA = -__expf(alF[ch * NSTATE + n]);
  float h = 0.f;
#pragma unroll
  for (int c = 0; c < NCHUNK; ++c) {
    size_t bc = (size_t)(b*NCHUNK + c);
    hin[(bc*DINNER + ch)*NSTATE + n] = h;
    float P = __expf(negA * Sd[bc*DINNER + ch]);
    h = P * h + Hc[(bc*DINNER + ch)*NSTATE + n];
  }
}

__global__ __launch_bounds__(256)
void emit_k(const float* __restrict__ delta,
            const __hip_bfloat16* __restrict__ xcH,
            const float* __restrict__ xdbl,
            const float* __restrict__ zsF,
            const float* __restrict__ alF,
            const float* __restrict__ DF,
            const float* __restrict__ hin,
            __hip_bfloat16* __restrict__ yH)
{
  __shared__ alignas(16) float BCs[CLEN*32];    // 8 KB
  const int bid  = blockIdx.x;
  const int b    = bid >> 9;
  const int c    = (bid >> 5) & (NCHUNK-1);
  const int cg   = bid & 31;
  const int tid  = threadIdx.x;
  const int lane = tid & 63;
  const int wave = tid >> 6;
  const int sub  = lane & 3;
  const int ch   = (cg << 6) + (wave << 4) + (lane >> 2);

  const size_t rb = (size_t)b * SEQ + (size_t)c * CLEN;

  for (int i = tid; i < CLEN*32; i += 256) {
    int t = i >> 5, j = i & 31;
    BCs[i] = xdbl[(rb + t)*96 + 64 + j];
  }
  __syncthreads();

  float negA[4];
#pragma unroll
  for (int j = 0; j < 4; ++j) negA[j] = -__expf(alF[ch*NSTATE + sub*4 + j]);
  const float Dch = DF[ch];

  const float*          dp = delta + rb * DINNER + ch;
  const __hip_bfloat16* xp = xcH   + rb * DINNER + ch;
  const float*          zp = zsF   + rb * DINNER + ch;
  __hip_bfloat16*       yp = yH    + rb * DINNER + ch;

  f32x4 hv = *(const f32x4*)&hin[((size_t)(b*NCHUNK + c)*DINNER + ch)*NSTATE + sub*4];
  float h0=hv.x, h1=hv.y, h2=hv.z, h3=hv.w;

  float d0[GSTEP], x0[GSTEP], z0[GSTEP], d1[GSTEP], x1[GSTEP], z1[GSTEP];

#define PF(D_,X_,Z_,T0) \
  _Pragma("unroll") \
  for (int u = 0; u < GSTEP; ++u) { \
    D_[u] = dp[(size_t)((T0)+u) * DINNER]; \
    X_[u] = bf2f(xp[(size_t)((T0)+u) * DINNER]); \
    Z_[u] = zp[(size_t)((T0)+u) * DINNER]; \
  }
#define STEPS(D_,X_,Z_,T0) \
  _Pragma("unroll") \
  for (int u = 0; u < GSTEP; ++u) { \
    float d_ = D_[u]; \
    float du = d_ * X_[u]; \
    f32x4 B4 = *(const f32x4*)&BCs[((T0)+u)*32 + sub*4]; \
    f32x4 C4 = *(const f32x4*)&BCs[((T0)+u)*32 + 16 + sub*4]; \
    h0 = __expf(d_*negA[0])*h0 + du*B4.x; \
    h1 = __expf(d_*negA[1])*h1 + du*B4.y; \
    h2 = __expf(d_*negA[2])*h2 + du*B4.z; \
    h3 = __expf(d_*negA[3])*h3 + du*B4.w; \
    float p = h0*C4.x + h1*C4.y + h2*C4.z + h3*C4.w; \
    p += __shfl_xor(p, 1); \
    p += __shfl_xor(p, 2); \
    if (sub == 0) { \
      float y = (p + X_[u] * Dch) * Z_[u]; \
      yp[(size_t)((T0)+u) * DINNER] = __float2bfloat16(y); \
    } \
  }

  PF(d0, x0, z0, 0)
  for (int t0 = 0; t0 < CLEN; t0 += 2*GSTEP) {
    PF(d1, x1, z1, t0 + GSTEP)
    STEPS(d0, x0, z0, t0)
    if (t0 + 2*GSTEP < CLEN) { PF(d0, x0, z0, t0 + 2*GSTEP) }
    STEPS(d1, x1, z1, t0 + GSTEP)
  }
#undef PF
#undef STEPS
}

// ---------------------------------------------------------------------------
extern "C" void kernel_launch(void* const* d_in, const int* in_sizes, int n_in,
                              void* d_out, int out_size, void* d_ws, size_t ws_size,
                              hipStream_t stream)
{
  float* out = (float*)d_out;   // reference output dtype: float32
  char* ws = (char*)d_ws;
  const size_t MB = 1024*1024;

  // workspace layout (68 MB, liveness-aliased)
  int*            flag    = (int*)            (ws);
  float*          cwF     = (float*)          (ws + 1024);
  float*          cbF     = (float*)          (ws + 40*1024);
  float*          dtbF    = (float*)          (ws + 56*1024);
  float*          alF     = (float*)          (ws + 72*1024);
  float*          DF      = (float*)          (ws + 208*1024);
  float*          Sd      = (float*)          (ws + 256*1024);      // 256 KB
  __hip_bfloat16* xB      = (__hip_bfloat16*) (ws + 1*MB);          // 4 MB  (dead after G1)
  __hip_bfloat16* inpB    = (__hip_bfloat16*) (ws + 5*MB);          // 8 MB  (dead after G1)
  __hip_bfloat16* xiB     = (__hip_bfloat16*) (ws + 13*MB);         // 8 MB  (dead after conv)
  float*          part    = (float*)          (ws + 1*MB);          // 12 MB aliases xB/inpB
  float*          dlt     = (float*)          (ws + 1*MB);          // 16 MB aliases part/xiB[:4MB]
  __hip_bfloat16* xprojB  = (__hip_bfloat16*) (ws + 21*MB);
  __hip_bfloat16* dtprojB = (__hip_bfloat16*) (ws + 21*MB + 512*1024);
  __hip_bfloat16* outpB   = (__hip_bfloat16*) (ws + 22*MB);         // 4 MB
  float*          zsF     = (float*)          (ws + 26*MB);         // 16 MB
  __hip_bfloat16* xcH     = (__hip_bfloat16*) (ws + 42*MB);         // 8 MB
  float*          xdbl    = (float*)          (ws + 50*MB);         // 768 KB
  __hip_bfloat16* dtH     = (__hip_bfloat16*) (ws + 51*MB);         // 256 KB
  __hip_bfloat16* yH      = (__hip_bfloat16*) (ws + 52*MB);         // 8 MB
  float*          Hc      = (float*)          (ws + 60*MB);         // 4 MB
  float*          hin     = (float*)          (ws + 64*MB);         // 4 MB -> top 68 MB

  dim3 blk(256);

  // 0) sniff (1 tiny block) + canonicalize (+ d_out zero-init)
  sniff_k<<<1, 64, 0, stream>>>((const unsigned short*)d_in[0], flag);
  CvtArgs ca = { d_in[0], d_in[1], d_in[2], d_in[3], d_in[4],
                 d_in[5], d_in[6], d_in[7], d_in[8], d_in[9],
                 xB, inpB, xprojB, dtprojB, outpB,
                 cwF, cbF, dtbF, alF, DF, out, flag };
  convert_all_k<<<CVT_TOT/256, blk, 0, stream>>>(ca);

  // 1) in_proj (2048 x 4096 x 1024): split -> xi bf16, silu(z) f32
  gemm64<4><<<dim3(4096/128, ROWS/128), blk, 0, stream>>>(
      xB, inpB, ROWS, 2*DINNER, DMODEL, 0, zsF, xiB, nullptr);

  // 2) xc = silu(depthwise_conv(xi) + b)
  conv_silu_k<<<(ROWS*DINNER)/256, blk, 0, stream>>>(xiB, cwF, cbF, xcH);

  // 3) x_dbl (2048 x 96 x 2048): 16-way split-K (kchunk=128 -> 2 iters) + reduce
  gemm64<5><<<dim3(1, ROWS/128, KSPLIT), blk, 0, stream>>>(
      xcH, xprojB, ROWS, 96, DINNER, DINNER/KSPLIT, part, nullptr, nullptr);
  reduce_xdbl_k<<<(ROWS*96+255)/256, blk, 0, stream>>>(part, xdbl, dtH);

  // 4) delta = softplus(dt @ dt_proj^T + dt_b) (2048 x 2048 x 64): single K-iter
  gemm64<3><<<dim3(DINNER/128, ROWS/128), blk, 0, stream>>>(
      dtH, dtprojB, ROWS, DINNER, DTRANK, 0, dlt, nullptr, dtbF);

  // 5) chunked selective scan + fused combine -> bf16 yH
  stats_k<<<BATCH*NCHUNK*32, blk, 0, stream>>>(dlt, xcH, xdbl, alF, Hc, Sd);
  carry_k<<<(BATCH*DINNER*NSTATE)/256, blk, 0, stream>>>(Hc, Sd, alF, hin);
  emit_k<<<BATCH*NCHUNK*32, blk, 0, stream>>>(dlt, xcH, xdbl, zsF, alF, DF, hin, yH);

  // 6) out_proj (2048 x 1024 x 2048): split-K=4, atomic accumulate into d_out
  gemm64<6><<<dim3(DMODEL/128, ROWS/128, 4), blk, 0, stream>>>(
      yH, outpB, ROWS, DMODEL, DINNER, DINNER/4, out, nullptr, nullptr);
}